// Round 13
// baseline (1332.979 us; speedup 1.0000x reference)
//
#include <hip/hip_runtime.h>
#include <hip/hip_bf16.h>

#define B_ 8
#define C_ 256
#define H_ 128
#define W_ 128
#define N_ 16384
#define KC_ 256
#define VC_ 256
#define HID_ 1024

typedef unsigned short ushort_t;
typedef __bf16 bf16x8 __attribute__((ext_vector_type(8)));
typedef float f32x4 __attribute__((ext_vector_type(4)));
typedef ushort_t u16x8 __attribute__((ext_vector_type(8)));

static __device__ __forceinline__ ushort_t f2bu(float f) {
  __hip_bfloat16 h = __float2bfloat16(f);
  return *reinterpret_cast<ushort_t*>(&h);
}
static __device__ __forceinline__ float bu2f(ushort_t u) {
  __hip_bfloat16 h;
  *reinterpret_cast<ushort_t*>(&h) = u;
  return __bfloat162float(h);
}

#define GLD16(gp, lp) __builtin_amdgcn_global_load_lds( \
    (const __attribute__((address_space(1))) void*)(gp), \
    (__attribute__((address_space(3))) void*)(lp), 16, 0, 0)

// ---------------- one-shot weight/bias packing
__global__ __launch_bounds__(256) void pack_all(
    const float* __restrict__ wk1, const float* __restrict__ wk2,
    const float* __restrict__ wq1, const float* __restrict__ wq2,
    const float* __restrict__ wv, const float* __restrict__ wfc1,
    const float* __restrict__ wfc2, const float* __restrict__ wdw,
    const float* __restrict__ bk1, const float* __restrict__ bk2,
    const float* __restrict__ bq1, const float* __restrict__ bq2,
    const float* __restrict__ bv, const float* __restrict__ wr,
    ushort_t* __restrict__ zbuf,
    float* __restrict__ bKV, float* __restrict__ bQ, float* __restrict__ wdwT,
    ushort_t* __restrict__ wvp, ushort_t* __restrict__ wfc1p,
    ushort_t* __restrict__ wfc2p, ushort_t* __restrict__ wrp,
    ushort_t* __restrict__ wkkp, ushort_t* __restrict__ wqqp) {
  int idx = blockIdx.x * 256 + threadIdx.x;
  const int MC = KC_ * C_;
  if (idx < 512) {
    zbuf[idx] = 0;
    bQ[idx] = (idx < 256) ? bq1[idx] : bq2[idx - 256];
    return;
  }
  idx -= 512;
  if (idx < 768) {
    bKV[idx] = (idx < 256) ? bk1[idx] : (idx < 512 ? bk2[idx - 256] : bv[idx - 512]);
    return;
  }
  idx -= 768;
  if (idx < 9216) { int c = idx / 9, t = idx % 9; wdwT[t * HID_ + c] = wdw[idx]; return; }
  idx -= 9216;
  if (idx < VC_ * C_) { wvp[idx] = f2bu(wv[idx]); return; }
  idx -= VC_ * C_;
  if (idx < HID_ * C_) { wfc1p[idx] = f2bu(wfc1[idx]); return; }
  idx -= HID_ * C_;
  if (idx < C_ * HID_) { wfc2p[idx] = f2bu(wfc2[idx]); return; }
  idx -= C_ * HID_;
  if (idx < C_ * 512) { wrp[idx] = f2bu(wr[idx]); return; }
  idx -= C_ * 512;
  if (idx < MC) {
    #pragma unroll
    for (int t = 0; t < 3; ++t) wkkp[t * MC + idx] = f2bu(wk1[idx * 3 + t]);
    return;
  }
  idx -= MC;
  if (idx < MC) {
    #pragma unroll
    for (int t = 0; t < 3; ++t) wkkp[3 * MC + t * MC + idx] = f2bu(wk2[idx * 3 + t]);
    return;
  }
  idx -= MC;
  if (idx < MC) {
    #pragma unroll
    for (int t = 0; t < 3; ++t) wqqp[t * MC + idx] = f2bu(wq1[idx * 3 + t]);
    return;
  }
  idx -= MC;
  if (idx < MC) {
    #pragma unroll
    for (int t = 0; t < 3; ++t) wqqp[3 * MC + t * MC + idx] = f2bu(wq2[idx * 3 + t]);
    return;
  }
}

// ---------------- fused LN1: x fp32 [c][n] -> bf16 [n][c]
__global__ __launch_bounds__(256) void ln1t_kernel(const float* __restrict__ x,
    const float* __restrict__ g, const float* __restrict__ beta,
    ushort_t* __restrict__ out) {
  __shared__ float T[256][67];
  __shared__ float st[2][4][64];
  __shared__ float mr[64], rs[64];
  int z = blockIdx.z;
  int n0 = blockIdx.x * 64;
  int t = threadIdx.x;
  const float* xb = x + (size_t)z * C_ * N_;
  #pragma unroll
  for (int j = 0; j < 16; ++j) {
    int e = (j * 256 + t) * 4;
    int c = e >> 6, n = e & 63;
    float4 v = *(const float4*)&xb[(size_t)c * N_ + n0 + n];
    T[c][n] = v.x; T[c][n + 1] = v.y; T[c][n + 2] = v.z; T[c][n + 3] = v.w;
  }
  __syncthreads();
  {
    int n = t & 63, part = t >> 6;
    float s1 = 0.f, s2 = 0.f;
    for (int c = part * 64; c < part * 64 + 64; ++c) { float v = T[c][n]; s1 += v; s2 += v * v; }
    st[0][part][n] = s1; st[1][part][n] = s2;
  }
  __syncthreads();
  if (t < 64) {
    float s1 = st[0][0][t] + st[0][1][t] + st[0][2][t] + st[0][3][t];
    float s2 = st[1][0][t] + st[1][1][t] + st[1][2][t] + st[1][3][t];
    float m = s1 * (1.f / C_);
    float v = s2 * (1.f / C_) - m * m;
    mr[t] = m; rs[t] = rsqrtf(v + 1e-5f);
  }
  __syncthreads();
  {
    int n = t >> 2, cc = (t & 3) * 64;
    float m = mr[n], r = rs[n];
    ushort_t* po = out + (size_t)z * N_ * C_ + (size_t)(n0 + n) * C_ + cc;
    #pragma unroll
    for (int j0 = 0; j0 < 64; j0 += 8) {
      u16x8 o;
      #pragma unroll
      for (int j = 0; j < 8; ++j) {
        int c = cc + j0 + j;
        o[j] = f2bu((T[c][n] - m) * r * g[c] + beta[c]);
      }
      *(u16x8*)(po + j0) = o;
    }
  }
}

// ---------------- fused LN2: tx bf16 [c][n] -> bf16 [n][c]
__global__ __launch_bounds__(256) void ln2t_kernel(const ushort_t* __restrict__ x,
    const float* __restrict__ g, const float* __restrict__ beta,
    ushort_t* __restrict__ out) {
  __shared__ ushort_t T[256][72];
  __shared__ float st[2][4][64];
  __shared__ float mr[64], rs[64];
  int z = blockIdx.z;
  int n0 = blockIdx.x * 64;
  int t = threadIdx.x;
  const ushort_t* xb = x + (size_t)z * C_ * N_;
  #pragma unroll
  for (int j = 0; j < 8; ++j) {
    int e = (j * 256 + t) * 8;
    int c = e >> 6, n = e & 63;
    *(u16x8*)&T[c][n] = *(const u16x8*)&xb[(size_t)c * N_ + n0 + n];
  }
  __syncthreads();
  {
    int n = t & 63, part = t >> 6;
    float s1 = 0.f, s2 = 0.f;
    for (int c = part * 64; c < part * 64 + 64; ++c) { float v = bu2f(T[c][n]); s1 += v; s2 += v * v; }
    st[0][part][n] = s1; st[1][part][n] = s2;
  }
  __syncthreads();
  if (t < 64) {
    float s1 = st[0][0][t] + st[0][1][t] + st[0][2][t] + st[0][3][t];
    float s2 = st[1][0][t] + st[1][1][t] + st[1][2][t] + st[1][3][t];
    float m = s1 * (1.f / C_);
    float v = s2 * (1.f / C_) - m * m;
    mr[t] = m; rs[t] = rsqrtf(v + 1e-5f);
  }
  __syncthreads();
  {
    int n = t >> 2, cc = (t & 3) * 64;
    float m = mr[n], r = rs[n];
    ushort_t* po = out + (size_t)z * N_ * C_ + (size_t)(n0 + n) * C_ + cc;
    #pragma unroll
    for (int j0 = 0; j0 < 64; j0 += 8) {
      u16x8 o;
      #pragma unroll
      for (int j = 0; j < 8; ++j) {
        int c = cc + j0 + j;
        o[j] = f2bu((bu2f(T[c][n]) - m) * r * g[c] + beta[c]);
      }
      *(u16x8*)(po + j0) = o;
    }
  }
}

// ======================= MFMA GEMM template =======================
// DIMSEL: 0 none; 1 w-shift; 2 h-shift; 3 dual-dir; 4 triple (K0 w, K1 h, val)
// BSOFT: B-loader applies channel-softmax from qstats (BDUAL only)
// ADUAL: z >= adualH selects A2/B2 operand bases and outB2 (merged dual-direction)
// BSTATS: OMODE2 epilogue emits per-row partial softmax stats (QQ)
// LDS = exactly 32768 B; epilogue runs in two half-tile passes.
template<int TAPS, int DIMSEL, int OMODE, int SPLIT, bool BDUAL, bool BSOFT, bool ADUAL, bool BSTATS>
__global__ __launch_bounds__(256) void mfma_gemm(
    const ushort_t* __restrict__ A, const ushort_t* __restrict__ A2,
    long Abatch, int lda, long Aplane, long Adirstride,
    const ushort_t* __restrict__ B, const ushort_t* __restrict__ B2, long Bbatch, int ldb,
    const float* __restrict__ bias,
    const float* __restrict__ resF, const ushort_t* __restrict__ resB, long Resbatch,
    float* __restrict__ outF, ushort_t* __restrict__ outB, ushort_t* __restrict__ outB2,
    ushort_t* __restrict__ outB3,
    long Outbatch, int ldo, int Ksteps, const ushort_t* __restrict__ zbuf,
    const float2* __restrict__ qstats, float2* __restrict__ pstats, int adualH) {
  __shared__ ushort_t sm[16384];
  int tid = threadIdx.x;
  int bx = blockIdx.x, by = blockIdx.y;
  int bzfull = blockIdx.z;
  bool adhi = ADUAL && (bzfull >= adualH);
  int bz = adhi ? bzfull - adualH : bzfull;
  if (gridDim.x == 128) bx = ((bx & 7) << 4) | (bx >> 3);
  int b = bz / SPLIT, sK = bz % SPLIT;
  long koff = (long)sK * Ksteps * 64;
  int dsel = (DIMSEL == 3) ? (by < 2 ? 1 : 2)
           : (DIMSEL == 4) ? (by < 2 ? 1 : (by < 4 ? 2 : 0))
           : DIMSEL;
  int m0 = (DIMSEL == 3 || DIMSEL == 4) ? ((by & 1) * 128) : (by * 128);
  int bofs = (DIMSEL == 3 || DIMSEL == 4) ? ((by >> 1) * 256) : 0;
  const ushort_t* Aroot = adhi ? A2 : A;
  const ushort_t* Broot = (!BDUAL && adhi) ? B2 : B;
  const ushort_t* Ab = Aroot + (size_t)b * Abatch + koff
      + ((DIMSEL == 3 || DIMSEL == 4) ? (long)(by >> 1) * Adirstride : 0L);
  const ushort_t* Bb = Broot + (size_t)b * Bbatch + (BDUAL ? 0 : koff);
  const ushort_t* B2b = BDUAL ? (B2 + (size_t)b * Bbatch) : nullptr;
  int n0 = bx * 128;
  int lane = tid & 63, wid = tid >> 6, wm = wid >> 1, wn = wid & 1;

  f32x4 acc[4][4];
  #pragma unroll
  for (int i = 0; i < 4; i++)
    #pragma unroll
    for (int j = 0; j < 4; j++) acc[i][j] = (f32x4)0.f;

  for (int t = 0; t < TAPS; ++t) {
    if (TAPS == 3 && dsel == 2) {
      if ((bx == 0 && t == 0) || (bx == H_ - 1 && t == 2)) continue;
    }
    if (DIMSEL == 4 && dsel == 0 && t != 1) continue;
    const ushort_t* At = Ab + ((DIMSEL == 4 && dsel == 0) ? 0L : (long)t * Aplane);
    for (int ks = 0; ks < Ksteps; ++ks) {
      int k0 = ks * 64;
      #pragma unroll
      for (int i = 0; i < 4; i++) {
        int s = tid + i * 256;
        int row = s >> 3, pc = s & 7;
        int lc = pc ^ (row & 7);
        const ushort_t* g = At + (long)(m0 + row) * lda + k0 + lc * 8;
        GLD16(g, &sm[s * 8]);
      }
      if (BDUAL && BSOFT) {
        int dir = (ks < Ksteps / 2) ? 0 : 1;
        const ushort_t* Bsel = dir ? B2b : Bb;
        int kb = (ks - dir * (Ksteps / 2)) * 64;
        #pragma unroll
        for (int i = 0; i < 4; i++) {
          int s = tid + i * 256;
          int row = s >> 3, pc = s & 7;
          int lc = pc ^ (row & 7);
          u16x8 e = *(const u16x8*)(Bsel + (long)(n0 + row) * ldb + kb + lc * 8);
          float2 st = qstats[(size_t)dir * B_ * N_ + (size_t)bz * N_ + n0 + row];
          u16x8 o;
          #pragma unroll
          for (int j = 0; j < 8; j++)
            o[j] = f2bu(__expf(bu2f(e[j]) - st.x) * st.y);
          *(u16x8*)&sm[8192 + s * 8] = o;
        }
      } else {
        #pragma unroll
        for (int i = 0; i < 4; i++) {
          int s = tid + i * 256;
          int row = s >> 3, pc = s & 7;
          int lc = pc ^ (row & 7);
          const ushort_t* g;
          if (BDUAL) {
            const ushort_t* Bsel = (ks < Ksteps / 2) ? Bb : B2b;
            int kb = ((ks < Ksteps / 2) ? ks : ks - Ksteps / 2) * 64;
            g = Bsel + (long)(n0 + row) * ldb + kb + lc * 8;
          } else if (TAPS == 3 && dsel == 1) {
            int wpos = row + (t - 1);
            if (0 <= wpos && wpos < W_)
              g = Bb + (long)(n0 + row + (t - 1)) * ldb + k0 + lc * 8;
            else
              g = zbuf;
          } else if (TAPS == 3 && dsel == 2) {
            g = Bb + (long)(n0 + row + (t - 1) * W_) * ldb + k0 + lc * 8;
          } else {
            g = Bb + (long)(n0 + row) * ldb + k0 + lc * 8;
          }
          GLD16(g, &sm[8192 + s * 8]);
        }
      }
      __syncthreads();
      #pragma unroll
      for (int kk = 0; kk < 2; kk++) {
        bf16x8 av[4], bv[4];
        int r16 = lane & 15;
        int sl = (lane >> 4) + kk * 4;
        #pragma unroll
        for (int fm = 0; fm < 4; fm++) {
          int row = wm * 64 + fm * 16 + r16;
          av[fm] = *(const bf16x8*)&sm[row * 64 + ((sl ^ (row & 7)) * 8)];
        }
        #pragma unroll
        for (int fn = 0; fn < 4; fn++) {
          int row = wn * 64 + fn * 16 + r16;
          bv[fn] = *(const bf16x8*)&sm[8192 + row * 64 + ((sl ^ (row & 7)) * 8)];
        }
        #pragma unroll
        for (int fm = 0; fm < 4; fm++)
          #pragma unroll
          for (int fn = 0; fn < 4; fn++)
            acc[fm][fn] = __builtin_amdgcn_mfma_f32_16x16x32_bf16(av[fm], bv[fn], acc[fm][fn], 0, 0, 0);
      }
      __syncthreads();
    }
  }

  int r16 = lane & 15, rq = lane >> 4;
  if (OMODE == 1 || OMODE == 2 || OMODE == 7) {
    ushort_t* obase;
    if (DIMSEL == 3 || DIMSEL == 4)
      obase = (blockIdx.y >= 4) ? outB3 : (blockIdx.y >= 2 ? outB2 : outB);
    else
      obase = adhi ? outB2 : outB;
    ushort_t* ob = obase + (size_t)bz * Outbatch;
    float smx = -1e30f, ssum = 0.f;         // BSTATS online accumulators
    #pragma unroll
    for (int hp = 0; hp < 2; ++hp) {
      __syncthreads();
      if (wm == hp) {
        #pragma unroll
        for (int fm = 0; fm < 4; fm++) {
          #pragma unroll
          for (int fn = 0; fn < 4; fn++) {
            int lml = fm * 16 + rq * 4;        // local m within half
            int lmg = hp * 64 + lml;           // m within tile
            int ln = wn * 64 + fn * 16 + r16;
            f32x4 a = acc[fm][fn];
            if (OMODE == 2) {
              #pragma unroll
              for (int r = 0; r < 4; r++)
                sm[ln * 72 + lml + r] = f2bu(a[r] + bias[bofs + m0 + lmg + r]);
            } else {
              #pragma unroll
              for (int r = 0; r < 4; r++)
                sm[(lml + r) * 136 + ln] = f2bu(a[r] + bias[bofs + m0 + lmg + r]);
            }
          }
        }
      }
      __syncthreads();
      if (OMODE == 2) {
        int row = tid >> 1;                    // n row 0..127
        int colb = (tid & 1) * 32;
        const ushort_t* src = &sm[row * 72 + colb];
        ushort_t* dst = &ob[(size_t)(n0 + row) * ldo + m0 + hp * 64 + colb];
        #pragma unroll
        for (int j = 0; j < 4; j++)
          *(u16x8*)(dst + j * 8) = *(const u16x8*)(src + j * 8);
        if (BSTATS) {
          float mxp = -1e30f;
          for (int j = 0; j < 32; ++j) mxp = fmaxf(mxp, bu2f(src[j]));
          float sp = 0.f;
          for (int j = 0; j < 32; ++j) sp += __expf(bu2f(src[j]) - mxp);
          float nm = fmaxf(smx, mxp);
          ssum = ssum * __expf(smx - nm) + sp * __expf(mxp - nm);
          smx = nm;
        }
      } else {
        int row = tid >> 2;                    // 0..63
        int qtr = (tid & 3) * 32;
        const ushort_t* src = &sm[row * 136 + qtr];
        ushort_t* dst = &ob[(size_t)(m0 + hp * 64 + row) * ldo + n0 + qtr];
        if (OMODE == 7) {
          const float* xb = resF + (size_t)bz * Resbatch
                          + (size_t)(m0 + hp * 64 + row) * ldo + n0 + qtr;
          #pragma unroll
          for (int j = 0; j < 4; j++) {
            u16x8 v = *(const u16x8*)(src + j * 8);
            float4 x0 = *(const float4*)(xb + j * 8);
            float4 x1 = *(const float4*)(xb + j * 8 + 4);
            u16x8 o;
            o[0] = f2bu(bu2f(v[0]) + x0.x); o[1] = f2bu(bu2f(v[1]) + x0.y);
            o[2] = f2bu(bu2f(v[2]) + x0.z); o[3] = f2bu(bu2f(v[3]) + x0.w);
            o[4] = f2bu(bu2f(v[4]) + x1.x); o[5] = f2bu(bu2f(v[5]) + x1.y);
            o[6] = f2bu(bu2f(v[6]) + x1.z); o[7] = f2bu(bu2f(v[7]) + x1.w);
            *(u16x8*)(dst + j * 8) = o;
          }
        } else {
          #pragma unroll
          for (int j = 0; j < 4; j++)
            *(u16x8*)(dst + j * 8) = *(const u16x8*)(src + j * 8);
        }
      }
    }
    if (OMODE == 2 && BSTATS) {
      float mo = __shfl_xor(smx, 1);
      float so = __shfl_xor(ssum, 1);
      float nm = fmaxf(smx, mo);
      float st = ssum * __expf(smx - nm) + so * __expf(mo - nm);
      if ((tid & 1) == 0) {
        int row = tid >> 1;
        int dir = by >> 1, hlf = by & 1;
        pstats[(((size_t)dir * B_ + bz) * N_ + n0 + row) * 2 + hlf] = make_float2(nm, st);
      }
    }
  } else {
    #pragma unroll
    for (int fm = 0; fm < 4; fm++) {
      #pragma unroll
      for (int fn = 0; fn < 4; fn++) {
        int mrow = m0 + wm * 64 + fm * 16 + rq * 4;
        int ncol = n0 + wn * 64 + fn * 16 + r16;
        f32x4 a = acc[fm][fn];
        if (OMODE == 6) {
          float* of = outF + (size_t)bzfull * Outbatch;
          #pragma unroll
          for (int r = 0; r < 4; r++)
            of[(size_t)(mrow + r) * ldo + ncol] = a[r];
        } else if (OMODE == 8) {
          float* of = outF + (size_t)bz * Outbatch;
          const ushort_t* rp = resB + (size_t)bz * Resbatch;
          #pragma unroll
          for (int r = 0; r < 4; r++) {
            size_t o = (size_t)(mrow + r) * ldo + ncol;
            of[o] = a[r] + bias[mrow + r] + bu2f(rp[o]);
          }
        }
      }
    }
  }
}

// ---------------- single-pass spatial softmax, exp cached in registers
__global__ __launch_bounds__(256) void softmax_spatial2(ushort_t* __restrict__ p0,
                                                        ushort_t* __restrict__ p1) {
  int r = blockIdx.x;
  ushort_t* p = (r < B_ * KC_) ? (p0 + (size_t)r * N_) : (p1 + (size_t)(r - B_ * KC_) * N_);
  int tid = threadIdx.x;
  __shared__ float red[256];
  u16x8 v[8];
  #pragma unroll
  for (int j = 0; j < 8; j++) v[j] = *(const u16x8*)&p[tid * 8 + j * 2048];
  float mx = -1e30f;
  #pragma unroll
  for (int j = 0; j < 8; j++)
    #pragma unroll
    for (int e = 0; e < 8; e++) mx = fmaxf(mx, bu2f(v[j][e]));
  red[tid] = mx; __syncthreads();
  for (int s = 128; s > 0; s >>= 1) { if (tid < s) red[tid] = fmaxf(red[tid], red[tid + s]); __syncthreads(); }
  mx = red[0]; __syncthreads();
  float ef[8][8];
  float sum = 0.f;
  #pragma unroll
  for (int j = 0; j < 8; j++)
    #pragma unroll
    for (int e = 0; e < 8; e++) { ef[j][e] = __expf(bu2f(v[j][e]) - mx); sum += ef[j][e]; }
  red[tid] = sum; __syncthreads();
  for (int s = 128; s > 0; s >>= 1) { if (tid < s) red[tid] += red[tid + s]; __syncthreads(); }
  float inv = 1.f / red[0];
  #pragma unroll
  for (int j = 0; j < 8; j++) {
    u16x8 o;
    #pragma unroll
    for (int e = 0; e < 8; e++) o[e] = f2bu(ef[j][e] * inv);
    *(u16x8*)&p[tid * 8 + j * 2048] = o;
  }
}

// ---------------- combine per-half partial stats -> qstats {max, 1/sum}
__global__ __launch_bounds__(256) void pcomb_kernel(const float2* __restrict__ pstats,
                                                    float2* __restrict__ qstats) {
  size_t idx = (size_t)blockIdx.x * 256 + threadIdx.x;   // 2*B*N rows
  float2 a = pstats[idx * 2 + 0];
  float2 b = pstats[idx * 2 + 1];
  float mx = fmaxf(a.x, b.x);
  float s = a.y * __expf(a.x - mx) + b.y * __expf(b.x - mx);
  qstats[idx] = make_float2(mx, 1.f / s);
}

// ---------------- amap: vectorized column sums, 4-way c-split, 512 n per block
__global__ __launch_bounds__(256) void amap2_kernel(const ushort_t* __restrict__ k0,
    const ushort_t* __restrict__ k1, float* __restrict__ amap) {
  __shared__ float red[256][8];
  int tid = threadIdx.x;
  int ngrp = tid & 63, part = tid >> 6;
  int nblock = blockIdx.x * 512;
  int b = nblock >> 14;
  int n = (nblock & 16383) + ngrp * 8;
  const ushort_t* b0 = k0 + (size_t)b * KC_ * N_ + n;
  const ushort_t* b1 = k1 + (size_t)b * KC_ * N_ + n;
  float s[8];
  #pragma unroll
  for (int j = 0; j < 8; j++) s[j] = 0.f;
  for (int c = part * 64; c < part * 64 + 64; ++c) {
    u16x8 a = *(const u16x8*)&b0[(size_t)c * N_];
    u16x8 d = *(const u16x8*)&b1[(size_t)c * N_];
    #pragma unroll
    for (int j = 0; j < 8; j++) s[j] += bu2f(a[j]) + bu2f(d[j]);
  }
  #pragma unroll
  for (int j = 0; j < 8; j++) red[tid][j] = s[j];
  __syncthreads();
  if (tid < 64) {
    float t[8];
    #pragma unroll
    for (int j = 0; j < 8; j++)
      t[j] = (red[tid][j] + red[tid + 64][j] + red[tid + 128][j] + red[tid + 192][j])
             * (1.f / (2.f * KC_));
    float* dst = amap + (size_t)nblock + tid * 8;
    *(float4*)dst = make_float4(t[0], t[1], t[2], t[3]);
    *(float4*)(dst + 4) = make_float4(t[4], t[5], t[6], t[7]);
  }
}

// ---------------- merged ctx split-K reduce (both dirs)
__global__ __launch_bounds__(256) void ctx_reduce2(const float* __restrict__ part,
                                                   float* __restrict__ ctxF,
                                                   ushort_t* __restrict__ c0b,
                                                   ushort_t* __restrict__ c1b) {
  int idx = blockIdx.x * 256 + threadIdx.x;     // 2 * B * 65536
  int dir = idx >> 19;
  int rem = idx & 524287;
  int b = rem >> 16;
  const float* p = part + ((size_t)(dir * 64 + b * 8)) * 65536 + (rem & 65535);
  float s = 0.f;
  #pragma unroll
  for (int k = 0; k < 8; k++) s += p[(size_t)k * 65536];
  if (dir == 0) c0b[rem] = f2bu(s);
  else { ctxF[rem] = s; c1b[rem] = f2bu(s); }
}

// ---------------- depthwise 3x3 + exact GELU in [n][hid]; blockIdx.y = batch-in-group
__global__ __launch_bounds__(256) void dwgelu_t(const ushort_t* __restrict__ h1t,
    const float* __restrict__ wdwT, const float* __restrict__ bdw,
    ushort_t* __restrict__ actT) {
  const ushort_t* h1 = h1t + (size_t)blockIdx.y * N_ * HID_;
  ushort_t* act = actT + (size_t)blockIdx.y * N_ * HID_;
  int pix = blockIdx.x * 2 + (threadIdx.x >> 7);
  int c = (threadIdx.x & 127) * 8;
  int h = pix >> 7, w = pix & 127;
  float s[8];
  {
    float4 b0 = *(const float4*)&bdw[c];
    float4 b1 = *(const float4*)&bdw[c + 4];
    s[0]=b0.x; s[1]=b0.y; s[2]=b0.z; s[3]=b0.w;
    s[4]=b1.x; s[5]=b1.y; s[6]=b1.z; s[7]=b1.w;
  }
  #pragma unroll
  for (int di = -1; di <= 1; ++di) {
    int h2 = h + di;
    if ((unsigned)h2 >= H_) continue;
    #pragma unroll
    for (int dj = -1; dj <= 1; ++dj) {
      int w2 = w + dj;
      if ((unsigned)w2 >= W_) continue;
      int tap = (di + 1) * 3 + (dj + 1);
      u16x8 v = *(const u16x8*)&h1[(size_t)(h2 * W_ + w2) * HID_ + c];
      const float* wp = &wdwT[tap * HID_ + c];
      float4 w0 = *(const float4*)wp, w1 = *(const float4*)(wp + 4);
      s[0] += w0.x * bu2f(v[0]); s[1] += w0.y * bu2f(v[1]);
      s[2] += w0.z * bu2f(v[2]); s[3] += w0.w * bu2f(v[3]);
      s[4] += w1.x * bu2f(v[4]); s[5] += w1.y * bu2f(v[5]);
      s[6] += w1.z * bu2f(v[6]); s[7] += w1.w * bu2f(v[7]);
    }
  }
  u16x8 o;
  #pragma unroll
  for (int j = 0; j < 8; j++) {
    float gl = 0.5f * s[j] * (1.f + erff(s[j] * 0.70710678118654752f));
    o[j] = f2bu(gl);
  }
  *(u16x8*)&act[(size_t)pix * HID_ + c] = o;
}

extern "C" void kernel_launch(void* const* d_in, const int* in_sizes, int n_in,
                              void* d_out, int out_size, void* d_ws, size_t ws_size,
                              hipStream_t stream) {
  const float* x    = (const float*)d_in[0];
  const float* wk1  = (const float*)d_in[3];
  const float* bk1  = (const float*)d_in[4];
  const float* wk2  = (const float*)d_in[5];
  const float* bk2  = (const float*)d_in[6];
  const float* wq1  = (const float*)d_in[7];
  const float* bq1  = (const float*)d_in[8];
  const float* wq2  = (const float*)d_in[9];
  const float* bq2  = (const float*)d_in[10];
  const float* wv   = (const float*)d_in[11];
  const float* bv   = (const float*)d_in[12];
  const float* wr   = (const float*)d_in[13];
  const float* br   = (const float*)d_in[14];
  const float* g1   = (const float*)d_in[15];
  const float* b1   = (const float*)d_in[16];
  const float* g2   = (const float*)d_in[17];
  const float* b2   = (const float*)d_in[18];
  const float* wfc1 = (const float*)d_in[19];
  const float* bfc1 = (const float*)d_in[20];
  const float* wdw  = (const float*)d_in[21];
  const float* bdw  = (const float*)d_in[22];
  const float* wfc2 = (const float*)d_in[23];
  const float* bfc2 = (const float*)d_in[24];

  const size_t big = (size_t)B_ * C_ * N_;
  const long  CN  = (long)C_ * N_;
  const long  NC2 = (long)N_ * C_;
  const long  NH  = (long)N_ * HID_;
  const int   MC  = KC_ * C_;

  uint8_t* w8 = (uint8_t*)d_ws;
  size_t off = 0;
  ushort_t* xnt  = (ushort_t*)(w8 + off); off += 67108864;
  ushort_t* kq   = (ushort_t*)(w8 + off); off += 67108864;
  ushort_t* Mbuf = (ushort_t*)(w8 + off); off += (size_t)B_ * C_ * 512 * 2;
  ushort_t* wkkp = (ushort_t*)(w8 + off); off += 6 * MC * 2;
  ushort_t* wvp  = (ushort_t*)(w8 + off); off += MC * 2;       // contiguous after wkkp
  ushort_t* wqqp = (ushort_t*)(w8 + off); off += 6 * MC * 2;
  ushort_t* wfc1p= (ushort_t*)(w8 + off); off += HID_ * C_ * 2;
  ushort_t* wfc2p= (ushort_t*)(w8 + off); off += C_ * HID_ * 2;
  float* wdwT    = (float*)(w8 + off);    off += 9 * HID_ * 4;
  float* bKV     = (float*)(w8 + off);    off += 768 * 4;
  float* bQ      = (float*)(w8 + off);    off += 512 * 4;
  ushort_t* wrp  = (ushort_t*)(w8 + off); off += C_ * 512 * 2;
  ushort_t* ctx0b= (ushort_t*)(w8 + off); off += (size_t)B_ * KC_ * VC_ * 2;
  ushort_t* ctx1b= (ushort_t*)(w8 + off); off += (size_t)B_ * KC_ * VC_ * 2;  // contiguous
  float2* qstats = (float2*)(w8 + off);   off += (size_t)2 * B_ * N_ * 8;
  float2* pstats = (float2*)(w8 + off);   off += (size_t)2 * B_ * N_ * 2 * 8;
  ushort_t* zbuf = (ushort_t*)(w8 + off); off += 2048;
  const size_t ctxpartBytes = (size_t)128 * KC_ * VC_ * 4;     // 33.55 MB
  const size_t txcopyBytes  = (size_t)2 * CN * 2;              // 16.78 MB
  size_t need_pair = off + 67108864 + txcopyBytes;
  size_t need_np   = off + ctxpartBytes;
  bool pairFFN;
  ushort_t* actX = nullptr;
  float* ctxpart;
  ushort_t* txcopy;
  if (ws_size >= need_pair) {
    pairFFN = true;
    actX = (ushort_t*)(w8 + off);
    ctxpart = (float*)(w8 + off);                     // aliases actX (disjoint in time)
    txcopy = (ushort_t*)(w8 + off + 67108864);
  } else if (ws_size >= need_np) {
    pairFFN = false;
    ctxpart = (float*)(w8 + off);
    txcopy = (ushort_t*)(w8 + off);                   // aliases ctxpart (disjoint in time)
  } else return;
  const float* fzero = (const float*)zbuf;

  float* mx_out   = (float*)d_out;
  float* ctx_out  = mx_out + big;
  float* amap_out = ctx_out + (size_t)B_ * KC_ * VC_;

  ushort_t* mxlo = (ushort_t*)d_out;            // val -> q1
  ushort_t* mxhi = (ushort_t*)d_out + big;      // K1 -> tx

  ushort_t* txn  = xnt;

  dim3 blk(256);

  pack_all<<<3881, blk, 0, stream>>>(wk1, wk2, wq1, wq2, wv, wfc1, wfc2, wdw,
                                     bk1, bk2, bq1, bq2, bv, wr,
                                     zbuf, bKV, bQ, wdwT,
                                     wvp, wfc1p, wfc2p, wrp, wkkp, wqqp);

  // LN1 fused
  ln1t_kernel<<<dim3(N_ / 64, 1, B_), blk, 0, stream>>>(x, g1, b1, xnt);

  // fused KKV: K0 -> kq, K1 -> mxhi, val -> mxlo
  mfma_gemm<3, 4, 1, 1, false, false, false, false><<<dim3(N_ / 128, 6, B_), blk, 0, stream>>>(
      wkkp, nullptr, 0, C_, (long)MC, (long)3 * MC, xnt, nullptr, NC2, C_,
      bKV, nullptr, nullptr, 0,
      nullptr, kq, mxhi, mxlo, (long)KC_ * N_, N_, C_ / 64, zbuf, nullptr, nullptr, 0);

  softmax_spatial2<<<2 * B_ * KC_, blk, 0, stream>>>(kq, mxhi);
  amap2_kernel<<<B_ * N_ / 512, blk, 0, stream>>>(kq, mxhi, amap_out);

  // merged ctx (both dirs, split-8): z in [0,64) dir0 (A=kq), [64,128) dir1 (A=mxhi)
  mfma_gemm<1, 0, 6, 8, false, false, true, false><<<dim3(VC_ / 128, KC_ / 128, 128), blk, 0, stream>>>(
      kq, mxhi, (long)KC_ * N_, N_, 0, 0, mxlo, mxlo, (long)VC_ * N_, N_,
      nullptr, nullptr, nullptr, 0,
      ctxpart, nullptr, nullptr, nullptr, (long)KC_ * VC_, VC_, (N_ / 8) / 64, zbuf,
      nullptr, nullptr, 64);
  ctx_reduce2<<<2 * B_ * KC_ * VC_ / 256, blk, 0, stream>>>(ctxpart, ctx_out, ctx0b, ctx1b);

  // fused QQ: q0 -> kq [n][kc], q1 -> mxlo; epilogue emits partial channel-softmax stats
  mfma_gemm<3, 3, 2, 1, false, false, false, true><<<dim3(N_ / 128, 4, B_), blk, 0, stream>>>(
      wqqp, nullptr, 0, C_, (long)MC, (long)3 * MC, xnt, nullptr, NC2, C_,
      bQ, nullptr, nullptr, 0,
      nullptr, kq, mxlo, nullptr, (long)N_ * KC_, KC_, C_ / 64, zbuf, nullptr, pstats, 0);

  pcomb_kernel<<<2 * B_ * N_ / 256, blk, 0, stream>>>(pstats, qstats);

  // merged Mcat: A=ctx (dir-switched), B=wr half (dir-switched), out [c][dir*256+kc]
  mfma_gemm<1, 0, 2, 1, false, false, true, false><<<dim3(C_ / 128, KC_ / 128, 16), blk, 0, stream>>>(
      ctx0b, ctx1b, (long)KC_ * VC_, VC_, 0, 0, wrp, wrp + 256, 0, 512,
      fzero, nullptr, nullptr, 0,
      nullptr, Mbuf, Mbuf + 256, nullptr, (long)C_ * 512, 512, VC_ / 64, zbuf,
      nullptr, nullptr, 8);

  // fused attention (softmax-in-loader) -> tx bf16 @ mxhi
  mfma_gemm<1, 0, 7, 1, true, true, false, false><<<dim3(N_ / 128, C_ / 128, B_), blk, 0, stream>>>(
      Mbuf, nullptr, (long)C_ * 512, 512, 0, 0, kq, mxlo, (long)N_ * KC_, KC_,
      br, x, nullptr, CN,
      nullptr, mxhi, nullptr, nullptr, CN, N_, 8, zbuf, qstats, nullptr, 0);

  // LN2 fused: tx -> txn
  ln2t_kernel<<<dim3(N_ / 64, 1, B_), blk, 0, stream>>>(mxhi, g2, b2, txn);

  if (pairFFN) {
    // copy tx b6,b7 (fc2 pair-3 writes clobber them)
    hipMemcpyAsync(txcopy, mxhi + (size_t)6 * CN, (size_t)2 * CN * 2,
                   hipMemcpyDeviceToDevice, stream);
    ushort_t* h1t2 = kq;           // 2 batches [N][HID]
    for (int g = 0; g < 4; ++g) {
      mfma_gemm<1, 0, 2, 1, false, false, false, false><<<dim3(N_ / 128, HID_ / 128, 2), blk, 0, stream>>>(
          wfc1p, nullptr, 0, C_, 0, 0, txn + (size_t)g * 2 * NC2, nullptr, NC2, C_,
          bfc1, nullptr, nullptr, 0,
          nullptr, h1t2, nullptr, nullptr, NH, HID_, C_ / 64, zbuf, nullptr, nullptr, 0);
      dwgelu_t<<<dim3(N_ / 2, 2), blk, 0, stream>>>(h1t2, wdwT, bdw, actX);
      const ushort_t* txb = (g == 3) ? (const ushort_t*)txcopy : (mxhi + (size_t)g * 2 * CN);
      mfma_gemm<1, 0, 8, 1, false, false, false, false><<<dim3(N_ / 128, C_ / 128, 2), blk, 0, stream>>>(
          wfc2p, nullptr, 0, HID_, 0, 0, actX, nullptr, NH, HID_,
          bfc2, nullptr, txb, CN,
          mx_out + (size_t)g * 2 * CN, nullptr, nullptr, nullptr, CN, N_, HID_ / 64, zbuf,
          nullptr, nullptr, 0);
    }
  } else {
    ushort_t* h1t  = kq;
    ushort_t* actT = kq + NH;
    hipMemcpyAsync(txcopy, mxhi + (size_t)7 * CN, (size_t)CN * 2,
                   hipMemcpyDeviceToDevice, stream);
    for (int b = 0; b < B_; ++b) {
      mfma_gemm<1, 0, 2, 1, false, false, false, false><<<dim3(N_ / 128, HID_ / 128, 1), blk, 0, stream>>>(
          wfc1p, nullptr, 0, C_, 0, 0, txn + (size_t)b * NC2, nullptr, 0, C_,
          bfc1, nullptr, nullptr, 0,
          nullptr, h1t, nullptr, nullptr, 0, HID_, C_ / 64, zbuf, nullptr, nullptr, 0);
      dwgelu_t<<<dim3(N_ / 2, 1), blk, 0, stream>>>(h1t, wdwT, bdw, actT);
      const ushort_t* txb = (b == 7) ? (const ushort_t*)txcopy : (mxhi + (size_t)b * CN);
      mfma_gemm<1, 0, 8, 1, false, false, false, false><<<dim3(N_ / 128, C_ / 128, 1), blk, 0, stream>>>(
          wfc2p, nullptr, 0, HID_, 0, 0, actT, nullptr, 0, HID_,
          bfc2, nullptr, txb, 0,
          mx_out + (size_t)b * CN, nullptr, nullptr, nullptr, 0, N_, HID_ / 64, zbuf,
          nullptr, nullptr, 0);
    }
  }
}

// Round 14
// 1282.019 us; speedup vs baseline: 1.0397x; 1.0397x over previous
//
#include <hip/hip_runtime.h>
#include <hip/hip_bf16.h>

#define B_ 8
#define C_ 256
#define H_ 128
#define W_ 128
#define N_ 16384
#define KC_ 256
#define VC_ 256
#define HID_ 1024

typedef unsigned short ushort_t;
typedef __bf16 bf16x8 __attribute__((ext_vector_type(8)));
typedef float f32x4 __attribute__((ext_vector_type(4)));
typedef ushort_t u16x8 __attribute__((ext_vector_type(8)));

static __device__ __forceinline__ ushort_t f2bu(float f) {
  __hip_bfloat16 h = __float2bfloat16(f);
  return *reinterpret_cast<ushort_t*>(&h);
}
static __device__ __forceinline__ float bu2f(ushort_t u) {
  __hip_bfloat16 h;
  *reinterpret_cast<ushort_t*>(&h) = u;
  return __bfloat162float(h);
}

#define GLD16(gp, lp) __builtin_amdgcn_global_load_lds( \
    (const __attribute__((address_space(1))) void*)(gp), \
    (__attribute__((address_space(3))) void*)(lp), 16, 0, 0)

// ---------------- one-shot weight/bias packing
__global__ __launch_bounds__(256) void pack_all(
    const float* __restrict__ wk1, const float* __restrict__ wk2,
    const float* __restrict__ wq1, const float* __restrict__ wq2,
    const float* __restrict__ wv, const float* __restrict__ wfc1,
    const float* __restrict__ wfc2, const float* __restrict__ wdw,
    const float* __restrict__ bk1, const float* __restrict__ bk2,
    const float* __restrict__ bq1, const float* __restrict__ bq2,
    const float* __restrict__ bv, const float* __restrict__ wr,
    ushort_t* __restrict__ zbuf,
    float* __restrict__ bKV, float* __restrict__ bQ, float* __restrict__ wdwT,
    ushort_t* __restrict__ wvp, ushort_t* __restrict__ wfc1p,
    ushort_t* __restrict__ wfc2p, ushort_t* __restrict__ wrp,
    ushort_t* __restrict__ wkkp, ushort_t* __restrict__ wqqp) {
  int idx = blockIdx.x * 256 + threadIdx.x;
  const int MC = KC_ * C_;
  if (idx < 512) {
    zbuf[idx] = 0;
    bQ[idx] = (idx < 256) ? bq1[idx] : bq2[idx - 256];
    return;
  }
  idx -= 512;
  if (idx < 768) {
    bKV[idx] = (idx < 256) ? bk1[idx] : (idx < 512 ? bk2[idx - 256] : bv[idx - 512]);
    return;
  }
  idx -= 768;
  if (idx < 9216) { int c = idx / 9, t = idx % 9; wdwT[t * HID_ + c] = wdw[idx]; return; }
  idx -= 9216;
  if (idx < VC_ * C_) { wvp[idx] = f2bu(wv[idx]); return; }
  idx -= VC_ * C_;
  if (idx < HID_ * C_) { wfc1p[idx] = f2bu(wfc1[idx]); return; }
  idx -= HID_ * C_;
  if (idx < C_ * HID_) { wfc2p[idx] = f2bu(wfc2[idx]); return; }
  idx -= C_ * HID_;
  if (idx < C_ * 512) { wrp[idx] = f2bu(wr[idx]); return; }
  idx -= C_ * 512;
  if (idx < MC) {
    #pragma unroll
    for (int t = 0; t < 3; ++t) wkkp[t * MC + idx] = f2bu(wk1[idx * 3 + t]);
    return;
  }
  idx -= MC;
  if (idx < MC) {
    #pragma unroll
    for (int t = 0; t < 3; ++t) wkkp[3 * MC + t * MC + idx] = f2bu(wk2[idx * 3 + t]);
    return;
  }
  idx -= MC;
  if (idx < MC) {
    #pragma unroll
    for (int t = 0; t < 3; ++t) wqqp[t * MC + idx] = f2bu(wq1[idx * 3 + t]);
    return;
  }
  idx -= MC;
  if (idx < MC) {
    #pragma unroll
    for (int t = 0; t < 3; ++t) wqqp[3 * MC + t * MC + idx] = f2bu(wq2[idx * 3 + t]);
    return;
  }
}

// ---------------- fused LN1: x fp32 [c][n] -> bf16 [n][c]
__global__ __launch_bounds__(256) void ln1t_kernel(const float* __restrict__ x,
    const float* __restrict__ g, const float* __restrict__ beta,
    ushort_t* __restrict__ out) {
  __shared__ float T[256][67];
  __shared__ float st[2][4][64];
  __shared__ float mr[64], rs[64];
  int z = blockIdx.z;
  int n0 = blockIdx.x * 64;
  int t = threadIdx.x;
  const float* xb = x + (size_t)z * C_ * N_;
  #pragma unroll
  for (int j = 0; j < 16; ++j) {
    int e = (j * 256 + t) * 4;
    int c = e >> 6, n = e & 63;
    float4 v = *(const float4*)&xb[(size_t)c * N_ + n0 + n];
    T[c][n] = v.x; T[c][n + 1] = v.y; T[c][n + 2] = v.z; T[c][n + 3] = v.w;
  }
  __syncthreads();
  {
    int n = t & 63, part = t >> 6;
    float s1 = 0.f, s2 = 0.f;
    for (int c = part * 64; c < part * 64 + 64; ++c) { float v = T[c][n]; s1 += v; s2 += v * v; }
    st[0][part][n] = s1; st[1][part][n] = s2;
  }
  __syncthreads();
  if (t < 64) {
    float s1 = st[0][0][t] + st[0][1][t] + st[0][2][t] + st[0][3][t];
    float s2 = st[1][0][t] + st[1][1][t] + st[1][2][t] + st[1][3][t];
    float m = s1 * (1.f / C_);
    float v = s2 * (1.f / C_) - m * m;
    mr[t] = m; rs[t] = rsqrtf(v + 1e-5f);
  }
  __syncthreads();
  {
    int n = t >> 2, cc = (t & 3) * 64;
    float m = mr[n], r = rs[n];
    ushort_t* po = out + (size_t)z * N_ * C_ + (size_t)(n0 + n) * C_ + cc;
    #pragma unroll
    for (int j0 = 0; j0 < 64; j0 += 8) {
      u16x8 o;
      #pragma unroll
      for (int j = 0; j < 8; ++j) {
        int c = cc + j0 + j;
        o[j] = f2bu((T[c][n] - m) * r * g[c] + beta[c]);
      }
      *(u16x8*)(po + j0) = o;
    }
  }
}

// ---------------- fused LN2: tx bf16 [c][n] -> bf16 [n][c]
__global__ __launch_bounds__(256) void ln2t_kernel(const ushort_t* __restrict__ x,
    const float* __restrict__ g, const float* __restrict__ beta,
    ushort_t* __restrict__ out) {
  __shared__ ushort_t T[256][72];
  __shared__ float st[2][4][64];
  __shared__ float mr[64], rs[64];
  int z = blockIdx.z;
  int n0 = blockIdx.x * 64;
  int t = threadIdx.x;
  const ushort_t* xb = x + (size_t)z * C_ * N_;
  #pragma unroll
  for (int j = 0; j < 8; ++j) {
    int e = (j * 256 + t) * 8;
    int c = e >> 6, n = e & 63;
    *(u16x8*)&T[c][n] = *(const u16x8*)&xb[(size_t)c * N_ + n0 + n];
  }
  __syncthreads();
  {
    int n = t & 63, part = t >> 6;
    float s1 = 0.f, s2 = 0.f;
    for (int c = part * 64; c < part * 64 + 64; ++c) { float v = bu2f(T[c][n]); s1 += v; s2 += v * v; }
    st[0][part][n] = s1; st[1][part][n] = s2;
  }
  __syncthreads();
  if (t < 64) {
    float s1 = st[0][0][t] + st[0][1][t] + st[0][2][t] + st[0][3][t];
    float s2 = st[1][0][t] + st[1][1][t] + st[1][2][t] + st[1][3][t];
    float m = s1 * (1.f / C_);
    float v = s2 * (1.f / C_) - m * m;
    mr[t] = m; rs[t] = rsqrtf(v + 1e-5f);
  }
  __syncthreads();
  {
    int n = t >> 2, cc = (t & 3) * 64;
    float m = mr[n], r = rs[n];
    ushort_t* po = out + (size_t)z * N_ * C_ + (size_t)(n0 + n) * C_ + cc;
    #pragma unroll
    for (int j0 = 0; j0 < 64; j0 += 8) {
      u16x8 o;
      #pragma unroll
      for (int j = 0; j < 8; ++j) {
        int c = cc + j0 + j;
        o[j] = f2bu((bu2f(T[c][n]) - m) * r * g[c] + beta[c]);
      }
      *(u16x8*)(po + j0) = o;
    }
  }
}

// ======================= MFMA GEMM template =======================
// DIMSEL: 0 none; 1 w-shift; 2 h-shift; 3 dual-dir; 4 triple (K0 w, K1 h, val)
// BSOFT: B-loader applies channel-softmax from qstats (BDUAL only)
// ADUAL: z >= adualH selects A2/B2 operand bases and outB2 (merged dual-direction)
// BSTATS: OMODE2 epilogue emits per-row partial softmax stats (QQ)
template<int TAPS, int DIMSEL, int OMODE, int SPLIT, bool BDUAL, bool BSOFT, bool ADUAL, bool BSTATS>
__global__ __launch_bounds__(256) void mfma_gemm(
    const ushort_t* __restrict__ A, const ushort_t* __restrict__ A2,
    long Abatch, int lda, long Aplane, long Adirstride,
    const ushort_t* __restrict__ B, const ushort_t* __restrict__ B2, long Bbatch, int ldb,
    const float* __restrict__ bias,
    const float* __restrict__ resF, const ushort_t* __restrict__ resB, long Resbatch,
    float* __restrict__ outF, ushort_t* __restrict__ outB, ushort_t* __restrict__ outB2,
    ushort_t* __restrict__ outB3,
    long Outbatch, int ldo, int Ksteps, const ushort_t* __restrict__ zbuf,
    const float2* __restrict__ qstats, float2* __restrict__ pstats, int adualH) {
  __shared__ ushort_t sm[17408];
  int tid = threadIdx.x;
  int bx = blockIdx.x, by = blockIdx.y;
  int bzfull = blockIdx.z;
  bool adhi = ADUAL && (bzfull >= adualH);
  int bz = adhi ? bzfull - adualH : bzfull;
  if (gridDim.x == 128) bx = ((bx & 7) << 4) | (bx >> 3);
  int b = bz / SPLIT, sK = bz % SPLIT;
  long koff = (long)sK * Ksteps * 64;
  int dsel = (DIMSEL == 3) ? (by < 2 ? 1 : 2)
           : (DIMSEL == 4) ? (by < 2 ? 1 : (by < 4 ? 2 : 0))
           : DIMSEL;
  int m0 = (DIMSEL == 3 || DIMSEL == 4) ? ((by & 1) * 128) : (by * 128);
  int bofs = (DIMSEL == 3 || DIMSEL == 4) ? ((by >> 1) * 256) : 0;
  const ushort_t* Aroot = adhi ? A2 : A;
  const ushort_t* Broot = (!BDUAL && adhi) ? B2 : B;
  const ushort_t* Ab = Aroot + (size_t)b * Abatch + koff
      + ((DIMSEL == 3 || DIMSEL == 4) ? (long)(by >> 1) * Adirstride : 0L);
  const ushort_t* Bb = Broot + (size_t)b * Bbatch + (BDUAL ? 0 : koff);
  const ushort_t* B2b = BDUAL ? (B2 + (size_t)b * Bbatch) : nullptr;
  int n0 = bx * 128;
  int lane = tid & 63, wid = tid >> 6, wm = wid >> 1, wn = wid & 1;

  f32x4 acc[4][4];
  #pragma unroll
  for (int i = 0; i < 4; i++)
    #pragma unroll
    for (int j = 0; j < 4; j++) acc[i][j] = (f32x4)0.f;

  for (int t = 0; t < TAPS; ++t) {
    if (TAPS == 3 && dsel == 2) {
      if ((bx == 0 && t == 0) || (bx == H_ - 1 && t == 2)) continue;
    }
    if (DIMSEL == 4 && dsel == 0 && t != 1) continue;
    const ushort_t* At = Ab + ((DIMSEL == 4 && dsel == 0) ? 0L : (long)t * Aplane);
    for (int ks = 0; ks < Ksteps; ++ks) {
      int k0 = ks * 64;
      #pragma unroll
      for (int i = 0; i < 4; i++) {
        int s = tid + i * 256;
        int row = s >> 3, pc = s & 7;
        int lc = pc ^ (row & 7);
        const ushort_t* g = At + (long)(m0 + row) * lda + k0 + lc * 8;
        GLD16(g, &sm[s * 8]);
      }
      if (BDUAL && BSOFT) {
        int dir = (ks < Ksteps / 2) ? 0 : 1;
        const ushort_t* Bsel = dir ? B2b : Bb;
        int kb = (ks - dir * (Ksteps / 2)) * 64;
        #pragma unroll
        for (int i = 0; i < 4; i++) {
          int s = tid + i * 256;
          int row = s >> 3, pc = s & 7;
          int lc = pc ^ (row & 7);
          u16x8 e = *(const u16x8*)(Bsel + (long)(n0 + row) * ldb + kb + lc * 8);
          float2 st = qstats[(size_t)dir * B_ * N_ + (size_t)bz * N_ + n0 + row];
          u16x8 o;
          #pragma unroll
          for (int j = 0; j < 8; j++)
            o[j] = f2bu(__expf(bu2f(e[j]) - st.x) * st.y);
          *(u16x8*)&sm[8192 + s * 8] = o;
        }
      } else {
        #pragma unroll
        for (int i = 0; i < 4; i++) {
          int s = tid + i * 256;
          int row = s >> 3, pc = s & 7;
          int lc = pc ^ (row & 7);
          const ushort_t* g;
          if (BDUAL) {
            const ushort_t* Bsel = (ks < Ksteps / 2) ? Bb : B2b;
            int kb = ((ks < Ksteps / 2) ? ks : ks - Ksteps / 2) * 64;
            g = Bsel + (long)(n0 + row) * ldb + kb + lc * 8;
          } else if (TAPS == 3 && dsel == 1) {
            int wpos = row + (t - 1);
            if (0 <= wpos && wpos < W_)
              g = Bb + (long)(n0 + row + (t - 1)) * ldb + k0 + lc * 8;
            else
              g = zbuf;
          } else if (TAPS == 3 && dsel == 2) {
            g = Bb + (long)(n0 + row + (t - 1) * W_) * ldb + k0 + lc * 8;
          } else {
            g = Bb + (long)(n0 + row) * ldb + k0 + lc * 8;
          }
          GLD16(g, &sm[8192 + s * 8]);
        }
      }
      __syncthreads();
      #pragma unroll
      for (int kk = 0; kk < 2; kk++) {
        bf16x8 av[4], bv[4];
        int r16 = lane & 15;
        int sl = (lane >> 4) + kk * 4;
        #pragma unroll
        for (int fm = 0; fm < 4; fm++) {
          int row = wm * 64 + fm * 16 + r16;
          av[fm] = *(const bf16x8*)&sm[row * 64 + ((sl ^ (row & 7)) * 8)];
        }
        #pragma unroll
        for (int fn = 0; fn < 4; fn++) {
          int row = wn * 64 + fn * 16 + r16;
          bv[fn] = *(const bf16x8*)&sm[8192 + row * 64 + ((sl ^ (row & 7)) * 8)];
        }
        #pragma unroll
        for (int fm = 0; fm < 4; fm++)
          #pragma unroll
          for (int fn = 0; fn < 4; fn++)
            acc[fm][fn] = __builtin_amdgcn_mfma_f32_16x16x32_bf16(av[fm], bv[fn], acc[fm][fn], 0, 0, 0);
      }
      __syncthreads();
    }
  }

  int r16 = lane & 15, rq = lane >> 4;
  if (OMODE == 1 || OMODE == 2 || OMODE == 7) {
    ushort_t* obase;
    if (DIMSEL == 3 || DIMSEL == 4)
      obase = (blockIdx.y >= 4) ? outB3 : (blockIdx.y >= 2 ? outB2 : outB);
    else
      obase = adhi ? outB2 : outB;
    ushort_t* ob = obase + (size_t)bz * Outbatch;
    #pragma unroll
    for (int fm = 0; fm < 4; fm++) {
      #pragma unroll
      for (int fn = 0; fn < 4; fn++) {
        int lm = wm * 64 + fm * 16 + rq * 4;
        int ln = wn * 64 + fn * 16 + r16;
        f32x4 a = acc[fm][fn];
        if (OMODE == 2) {
          #pragma unroll
          for (int r = 0; r < 4; r++)
            sm[ln * 136 + lm + r] = f2bu(a[r] + bias[bofs + m0 + lm + r]);
        } else {
          #pragma unroll
          for (int r = 0; r < 4; r++)
            sm[(lm + r) * 136 + ln] = f2bu(a[r] + bias[bofs + m0 + lm + r]);
        }
      }
    }
    __syncthreads();
    int row = tid >> 1, half = (tid & 1) * 64;
    const ushort_t* src = &sm[row * 136 + half];
    if (OMODE == 7) {
      const float* xb = resF + (size_t)bz * Resbatch + (size_t)(m0 + row) * ldo + n0 + half;
      ushort_t* dst = &ob[(size_t)(m0 + row) * ldo + n0 + half];
      #pragma unroll
      for (int j = 0; j < 8; j++) {
        u16x8 v = *(const u16x8*)(src + j * 8);
        float4 x0 = *(const float4*)(xb + j * 8);
        float4 x1 = *(const float4*)(xb + j * 8 + 4);
        u16x8 o;
        o[0] = f2bu(bu2f(v[0]) + x0.x); o[1] = f2bu(bu2f(v[1]) + x0.y);
        o[2] = f2bu(bu2f(v[2]) + x0.z); o[3] = f2bu(bu2f(v[3]) + x0.w);
        o[4] = f2bu(bu2f(v[4]) + x1.x); o[5] = f2bu(bu2f(v[5]) + x1.y);
        o[6] = f2bu(bu2f(v[6]) + x1.z); o[7] = f2bu(bu2f(v[7]) + x1.w);
        *(u16x8*)(dst + j * 8) = o;
      }
    } else {
      ushort_t* dst;
      if (OMODE == 1) dst = &ob[(size_t)(m0 + row) * ldo + n0 + half];
      else            dst = &ob[(size_t)(n0 + row) * ldo + m0 + half];
      #pragma unroll
      for (int j = 0; j < 8; j++)
        *(u16x8*)(dst + j * 8) = *(const u16x8*)(src + j * 8);
    }
    if (OMODE == 2 && BSTATS) {
      int colb = (tid & 1) * 64;
      const ushort_t* rp = &sm[row * 136 + colb];
      float mxl = -1e30f;
      for (int j = 0; j < 64; ++j) mxl = fmaxf(mxl, bu2f(rp[j]));
      float mxh = fmaxf(mxl, __shfl_xor(mxl, 1));
      float s = 0.f;
      for (int j = 0; j < 64; ++j) s += __expf(bu2f(rp[j]) - mxh);
      s += __shfl_xor(s, 1);
      if ((tid & 1) == 0) {
        int dir = by >> 1, hlf = by & 1;
        pstats[(((size_t)dir * B_ + bz) * N_ + n0 + row) * 2 + hlf] = make_float2(mxh, s);
      }
    }
  } else {
    #pragma unroll
    for (int fm = 0; fm < 4; fm++) {
      #pragma unroll
      for (int fn = 0; fn < 4; fn++) {
        int mrow = m0 + wm * 64 + fm * 16 + rq * 4;
        int ncol = n0 + wn * 64 + fn * 16 + r16;
        f32x4 a = acc[fm][fn];
        if (OMODE == 6) {
          float* of = outF + (size_t)bzfull * Outbatch;
          #pragma unroll
          for (int r = 0; r < 4; r++)
            of[(size_t)(mrow + r) * ldo + ncol] = a[r];
        } else if (OMODE == 8) {
          float* of = outF + (size_t)bz * Outbatch;
          const ushort_t* rp = resB + (size_t)bz * Resbatch;
          #pragma unroll
          for (int r = 0; r < 4; r++) {
            size_t o = (size_t)(mrow + r) * ldo + ncol;
            of[o] = a[r] + bias[mrow + r] + bu2f(rp[o]);
          }
        }
      }
    }
  }
}

// ---------------- single-pass spatial softmax, exp cached in registers
__global__ __launch_bounds__(256) void softmax_spatial2(ushort_t* __restrict__ p0,
                                                        ushort_t* __restrict__ p1) {
  int r = blockIdx.x;
  ushort_t* p = (r < B_ * KC_) ? (p0 + (size_t)r * N_) : (p1 + (size_t)(r - B_ * KC_) * N_);
  int tid = threadIdx.x;
  __shared__ float red[256];
  u16x8 v[8];
  #pragma unroll
  for (int j = 0; j < 8; j++) v[j] = *(const u16x8*)&p[tid * 8 + j * 2048];
  float mx = -1e30f;
  #pragma unroll
  for (int j = 0; j < 8; j++)
    #pragma unroll
    for (int e = 0; e < 8; e++) mx = fmaxf(mx, bu2f(v[j][e]));
  red[tid] = mx; __syncthreads();
  for (int s = 128; s > 0; s >>= 1) { if (tid < s) red[tid] = fmaxf(red[tid], red[tid + s]); __syncthreads(); }
  mx = red[0]; __syncthreads();
  float ef[8][8];
  float sum = 0.f;
  #pragma unroll
  for (int j = 0; j < 8; j++)
    #pragma unroll
    for (int e = 0; e < 8; e++) { ef[j][e] = __expf(bu2f(v[j][e]) - mx); sum += ef[j][e]; }
  red[tid] = sum; __syncthreads();
  for (int s = 128; s > 0; s >>= 1) { if (tid < s) red[tid] += red[tid + s]; __syncthreads(); }
  float inv = 1.f / red[0];
  #pragma unroll
  for (int j = 0; j < 8; j++) {
    u16x8 o;
    #pragma unroll
    for (int e = 0; e < 8; e++) o[e] = f2bu(ef[j][e] * inv);
    *(u16x8*)&p[tid * 8 + j * 2048] = o;
  }
}

// ---------------- combine per-half partial stats -> qstats {max, 1/sum}
__global__ __launch_bounds__(256) void pcomb_kernel(const float2* __restrict__ pstats,
                                                    float2* __restrict__ qstats) {
  size_t idx = (size_t)blockIdx.x * 256 + threadIdx.x;   // 2*B*N rows
  float2 a = pstats[idx * 2 + 0];
  float2 b = pstats[idx * 2 + 1];
  float mx = fmaxf(a.x, b.x);
  float s = a.y * __expf(a.x - mx) + b.y * __expf(b.x - mx);
  qstats[idx] = make_float2(mx, 1.f / s);
}

// ---------------- amap: vectorized column sums, 4-way c-split, 512 n per block
__global__ __launch_bounds__(256) void amap2_kernel(const ushort_t* __restrict__ k0,
    const ushort_t* __restrict__ k1, float* __restrict__ amap) {
  __shared__ float red[256][8];
  int tid = threadIdx.x;
  int ngrp = tid & 63, part = tid >> 6;
  int nblock = blockIdx.x * 512;
  int b = nblock >> 14;
  int n = (nblock & 16383) + ngrp * 8;
  const ushort_t* b0 = k0 + (size_t)b * KC_ * N_ + n;
  const ushort_t* b1 = k1 + (size_t)b * KC_ * N_ + n;
  float s[8];
  #pragma unroll
  for (int j = 0; j < 8; j++) s[j] = 0.f;
  for (int c = part * 64; c < part * 64 + 64; ++c) {
    u16x8 a = *(const u16x8*)&b0[(size_t)c * N_];
    u16x8 d = *(const u16x8*)&b1[(size_t)c * N_];
    #pragma unroll
    for (int j = 0; j < 8; j++) s[j] += bu2f(a[j]) + bu2f(d[j]);
  }
  #pragma unroll
  for (int j = 0; j < 8; j++) red[tid][j] = s[j];
  __syncthreads();
  if (tid < 64) {
    float t[8];
    #pragma unroll
    for (int j = 0; j < 8; j++)
      t[j] = (red[tid][j] + red[tid + 64][j] + red[tid + 128][j] + red[tid + 192][j])
             * (1.f / (2.f * KC_));
    float* dst = amap + (size_t)nblock + tid * 8;
    *(float4*)dst = make_float4(t[0], t[1], t[2], t[3]);
    *(float4*)(dst + 4) = make_float4(t[4], t[5], t[6], t[7]);
  }
}

// ---------------- merged ctx split-K reduce (both dirs)
__global__ __launch_bounds__(256) void ctx_reduce2(const float* __restrict__ part,
                                                   float* __restrict__ ctxF,
                                                   ushort_t* __restrict__ c0b,
                                                   ushort_t* __restrict__ c1b) {
  int idx = blockIdx.x * 256 + threadIdx.x;     // 2 * B * 65536
  int dir = idx >> 19;
  int rem = idx & 524287;
  int b = rem >> 16;
  const float* p = part + ((size_t)(dir * 64 + b * 8)) * 65536 + (rem & 65535);
  float s = 0.f;
  #pragma unroll
  for (int k = 0; k < 8; k++) s += p[(size_t)k * 65536];
  if (dir == 0) c0b[rem] = f2bu(s);
  else { ctxF[rem] = s; c1b[rem] = f2bu(s); }
}

// ---------------- depthwise 3x3 + exact GELU in [n][hid]; blockIdx.y = batch-in-group
__global__ __launch_bounds__(256) void dwgelu_t(const ushort_t* __restrict__ h1t,
    const float* __restrict__ wdwT, const float* __restrict__ bdw,
    ushort_t* __restrict__ actT) {
  const ushort_t* h1 = h1t + (size_t)blockIdx.y * N_ * HID_;
  ushort_t* act = actT + (size_t)blockIdx.y * N_ * HID_;
  int pix = blockIdx.x * 2 + (threadIdx.x >> 7);
  int c = (threadIdx.x & 127) * 8;
  int h = pix >> 7, w = pix & 127;
  float s[8];
  {
    float4 b0 = *(const float4*)&bdw[c];
    float4 b1 = *(const float4*)&bdw[c + 4];
    s[0]=b0.x; s[1]=b0.y; s[2]=b0.z; s[3]=b0.w;
    s[4]=b1.x; s[5]=b1.y; s[6]=b1.z; s[7]=b1.w;
  }
  #pragma unroll
  for (int di = -1; di <= 1; ++di) {
    int h2 = h + di;
    if ((unsigned)h2 >= H_) continue;
    #pragma unroll
    for (int dj = -1; dj <= 1; ++dj) {
      int w2 = w + dj;
      if ((unsigned)w2 >= W_) continue;
      int tap = (di + 1) * 3 + (dj + 1);
      u16x8 v = *(const u16x8*)&h1[(size_t)(h2 * W_ + w2) * HID_ + c];
      const float* wp = &wdwT[tap * HID_ + c];
      float4 w0 = *(const float4*)wp, w1 = *(const float4*)(wp + 4);
      s[0] += w0.x * bu2f(v[0]); s[1] += w0.y * bu2f(v[1]);
      s[2] += w0.z * bu2f(v[2]); s[3] += w0.w * bu2f(v[3]);
      s[4] += w1.x * bu2f(v[4]); s[5] += w1.y * bu2f(v[5]);
      s[6] += w1.z * bu2f(v[6]); s[7] += w1.w * bu2f(v[7]);
    }
  }
  u16x8 o;
  #pragma unroll
  for (int j = 0; j < 8; j++) {
    float gl = 0.5f * s[j] * (1.f + erff(s[j] * 0.70710678118654752f));
    o[j] = f2bu(gl);
  }
  *(u16x8*)&act[(size_t)pix * HID_ + c] = o;
}

extern "C" void kernel_launch(void* const* d_in, const int* in_sizes, int n_in,
                              void* d_out, int out_size, void* d_ws, size_t ws_size,
                              hipStream_t stream) {
  const float* x    = (const float*)d_in[0];
  const float* wk1  = (const float*)d_in[3];
  const float* bk1  = (const float*)d_in[4];
  const float* wk2  = (const float*)d_in[5];
  const float* bk2  = (const float*)d_in[6];
  const float* wq1  = (const float*)d_in[7];
  const float* bq1  = (const float*)d_in[8];
  const float* wq2  = (const float*)d_in[9];
  const float* bq2  = (const float*)d_in[10];
  const float* wv   = (const float*)d_in[11];
  const float* bv   = (const float*)d_in[12];
  const float* wr   = (const float*)d_in[13];
  const float* br   = (const float*)d_in[14];
  const float* g1   = (const float*)d_in[15];
  const float* b1   = (const float*)d_in[16];
  const float* g2   = (const float*)d_in[17];
  const float* b2   = (const float*)d_in[18];
  const float* wfc1 = (const float*)d_in[19];
  const float* bfc1 = (const float*)d_in[20];
  const float* wdw  = (const float*)d_in[21];
  const float* bdw  = (const float*)d_in[22];
  const float* wfc2 = (const float*)d_in[23];
  const float* bfc2 = (const float*)d_in[24];

  const size_t big = (size_t)B_ * C_ * N_;
  const long  CN  = (long)C_ * N_;
  const long  NC2 = (long)N_ * C_;
  const long  NH  = (long)N_ * HID_;
  const int   MC  = KC_ * C_;

  uint8_t* w8 = (uint8_t*)d_ws;
  size_t off = 0;
  ushort_t* xnt  = (ushort_t*)(w8 + off); off += 67108864;
  ushort_t* kq   = (ushort_t*)(w8 + off); off += 67108864;
  ushort_t* Mbuf = (ushort_t*)(w8 + off); off += (size_t)B_ * C_ * 512 * 2;
  ushort_t* wkkp = (ushort_t*)(w8 + off); off += 6 * MC * 2;
  ushort_t* wvp  = (ushort_t*)(w8 + off); off += MC * 2;       // contiguous after wkkp
  ushort_t* wqqp = (ushort_t*)(w8 + off); off += 6 * MC * 2;
  ushort_t* wfc1p= (ushort_t*)(w8 + off); off += HID_ * C_ * 2;
  ushort_t* wfc2p= (ushort_t*)(w8 + off); off += C_ * HID_ * 2;
  float* wdwT    = (float*)(w8 + off);    off += 9 * HID_ * 4;
  float* bKV     = (float*)(w8 + off);    off += 768 * 4;
  float* bQ      = (float*)(w8 + off);    off += 512 * 4;
  ushort_t* wrp  = (ushort_t*)(w8 + off); off += C_ * 512 * 2;
  ushort_t* ctx0b= (ushort_t*)(w8 + off); off += (size_t)B_ * KC_ * VC_ * 2;
  ushort_t* ctx1b= (ushort_t*)(w8 + off); off += (size_t)B_ * KC_ * VC_ * 2;  // contiguous
  float2* qstats = (float2*)(w8 + off);   off += (size_t)2 * B_ * N_ * 8;
  float2* pstats = (float2*)(w8 + off);   off += (size_t)2 * B_ * N_ * 2 * 8;
  ushort_t* zbuf = (ushort_t*)(w8 + off); off += 2048;
  const size_t ctxpartBytes = (size_t)128 * KC_ * VC_ * 4;     // 33.55 MB
  const size_t txcopyBytes  = (size_t)2 * CN * 2;              // 16.78 MB
  size_t need_pair = off + 67108864 + txcopyBytes;
  size_t need_np   = off + ctxpartBytes;
  bool pairFFN;
  ushort_t* actX = nullptr;
  float* ctxpart;
  ushort_t* txcopy;
  if (ws_size >= need_pair) {
    pairFFN = true;
    actX = (ushort_t*)(w8 + off);
    ctxpart = (float*)(w8 + off);                     // aliases actX (disjoint in time)
    txcopy = (ushort_t*)(w8 + off + 67108864);
  } else if (ws_size >= need_np) {
    pairFFN = false;
    ctxpart = (float*)(w8 + off);
    txcopy = (ushort_t*)(w8 + off);                   // aliases ctxpart (disjoint in time)
  } else return;
  const float* fzero = (const float*)zbuf;

  float* mx_out   = (float*)d_out;
  float* ctx_out  = mx_out + big;
  float* amap_out = ctx_out + (size_t)B_ * KC_ * VC_;

  ushort_t* mxlo = (ushort_t*)d_out;            // val -> q1
  ushort_t* mxhi = (ushort_t*)d_out + big;      // K1 -> tx

  ushort_t* txn  = xnt;

  dim3 blk(256);

  pack_all<<<3881, blk, 0, stream>>>(wk1, wk2, wq1, wq2, wv, wfc1, wfc2, wdw,
                                     bk1, bk2, bq1, bq2, bv, wr,
                                     zbuf, bKV, bQ, wdwT,
                                     wvp, wfc1p, wfc2p, wrp, wkkp, wqqp);

  // LN1 fused
  ln1t_kernel<<<dim3(N_ / 64, 1, B_), blk, 0, stream>>>(x, g1, b1, xnt);

  // fused KKV: K0 -> kq, K1 -> mxhi, val -> mxlo
  mfma_gemm<3, 4, 1, 1, false, false, false, false><<<dim3(N_ / 128, 6, B_), blk, 0, stream>>>(
      wkkp, nullptr, 0, C_, (long)MC, (long)3 * MC, xnt, nullptr, NC2, C_,
      bKV, nullptr, nullptr, 0,
      nullptr, kq, mxhi, mxlo, (long)KC_ * N_, N_, C_ / 64, zbuf, nullptr, nullptr, 0);

  softmax_spatial2<<<2 * B_ * KC_, blk, 0, stream>>>(kq, mxhi);
  amap2_kernel<<<B_ * N_ / 512, blk, 0, stream>>>(kq, mxhi, amap_out);

  // merged ctx (both dirs, split-8): z in [0,64) dir0 (A=kq), [64,128) dir1 (A=mxhi)
  mfma_gemm<1, 0, 6, 8, false, false, true, false><<<dim3(VC_ / 128, KC_ / 128, 128), blk, 0, stream>>>(
      kq, mxhi, (long)KC_ * N_, N_, 0, 0, mxlo, mxlo, (long)VC_ * N_, N_,
      nullptr, nullptr, nullptr, 0,
      ctxpart, nullptr, nullptr, nullptr, (long)KC_ * VC_, VC_, (N_ / 8) / 64, zbuf,
      nullptr, nullptr, 64);
  ctx_reduce2<<<2 * B_ * KC_ * VC_ / 256, blk, 0, stream>>>(ctxpart, ctx_out, ctx0b, ctx1b);

  // fused QQ: q0 -> kq [n][kc], q1 -> mxlo; epilogue emits partial channel-softmax stats
  mfma_gemm<3, 3, 2, 1, false, false, false, true><<<dim3(N_ / 128, 4, B_), blk, 0, stream>>>(
      wqqp, nullptr, 0, C_, (long)MC, (long)3 * MC, xnt, nullptr, NC2, C_,
      bQ, nullptr, nullptr, 0,
      nullptr, kq, mxlo, nullptr, (long)N_ * KC_, KC_, C_ / 64, zbuf, nullptr, pstats, 0);

  pcomb_kernel<<<2 * B_ * N_ / 256, blk, 0, stream>>>(pstats, qstats);

  // merged Mcat: A=ctx (dir-switched), B=wr half (dir-switched), out [c][dir*256+kc]
  mfma_gemm<1, 0, 2, 1, false, false, true, false><<<dim3(C_ / 128, KC_ / 128, 16), blk, 0, stream>>>(
      ctx0b, ctx1b, (long)KC_ * VC_, VC_, 0, 0, wrp, wrp + 256, 0, 512,
      fzero, nullptr, nullptr, 0,
      nullptr, Mbuf, Mbuf + 256, nullptr, (long)C_ * 512, 512, VC_ / 64, zbuf,
      nullptr, nullptr, 8);

  // fused attention (softmax-in-loader) -> tx bf16 @ mxhi
  mfma_gemm<1, 0, 7, 1, true, true, false, false><<<dim3(N_ / 128, C_ / 128, B_), blk, 0, stream>>>(
      Mbuf, nullptr, (long)C_ * 512, 512, 0, 0, kq, mxlo, (long)N_ * KC_, KC_,
      br, x, nullptr, CN,
      nullptr, mxhi, nullptr, nullptr, CN, N_, 8, zbuf, qstats, nullptr, 0);

  // LN2 fused: tx -> txn
  ln2t_kernel<<<dim3(N_ / 64, 1, B_), blk, 0, stream>>>(mxhi, g2, b2, txn);

  if (pairFFN) {
    // copy tx b6,b7 (fc2 pair-3 writes clobber them)
    hipMemcpyAsync(txcopy, mxhi + (size_t)6 * CN, (size_t)2 * CN * 2,
                   hipMemcpyDeviceToDevice, stream);
    ushort_t* h1t2 = kq;           // 2 batches [N][HID]
    for (int g = 0; g < 4; ++g) {
      mfma_gemm<1, 0, 2, 1, false, false, false, false><<<dim3(N_ / 128, HID_ / 128, 2), blk, 0, stream>>>(
          wfc1p, nullptr, 0, C_, 0, 0, txn + (size_t)g * 2 * NC2, nullptr, NC2, C_,
          bfc1, nullptr, nullptr, 0,
          nullptr, h1t2, nullptr, nullptr, NH, HID_, C_ / 64, zbuf, nullptr, nullptr, 0);
      dwgelu_t<<<dim3(N_ / 2, 2), blk, 0, stream>>>(h1t2, wdwT, bdw, actX);
      const ushort_t* txb = (g == 3) ? (const ushort_t*)txcopy : (mxhi + (size_t)g * 2 * CN);
      mfma_gemm<1, 0, 8, 1, false, false, false, false><<<dim3(N_ / 128, C_ / 128, 2), blk, 0, stream>>>(
          wfc2p, nullptr, 0, HID_, 0, 0, actX, nullptr, NH, HID_,
          bfc2, nullptr, txb, CN,
          mx_out + (size_t)g * 2 * CN, nullptr, nullptr, nullptr, CN, N_, HID_ / 64, zbuf,
          nullptr, nullptr, 0);
    }
  } else {
    ushort_t* h1t  = kq;
    ushort_t* actT = kq + NH;
    hipMemcpyAsync(txcopy, mxhi + (size_t)7 * CN, (size_t)CN * 2,
                   hipMemcpyDeviceToDevice, stream);
    for (int b = 0; b < B_; ++b) {
      mfma_gemm<1, 0, 2, 1, false, false, false, false><<<dim3(N_ / 128, HID_ / 128, 1), blk, 0, stream>>>(
          wfc1p, nullptr, 0, C_, 0, 0, txn + (size_t)b * NC2, nullptr, 0, C_,
          bfc1, nullptr, nullptr, 0,
          nullptr, h1t, nullptr, nullptr, 0, HID_, C_ / 64, zbuf, nullptr, nullptr, 0);
      dwgelu_t<<<dim3(N_ / 2, 1), blk, 0, stream>>>(h1t, wdwT, bdw, actT);
      const ushort_t* txb = (b == 7) ? (const ushort_t*)txcopy : (mxhi + (size_t)b * CN);
      mfma_gemm<1, 0, 8, 1, false, false, false, false><<<dim3(N_ / 128, C_ / 128, 1), blk, 0, stream>>>(
          wfc2p, nullptr, 0, HID_, 0, 0, actT, nullptr, 0, HID_,
          bfc2, nullptr, txb, 0,
          mx_out + (size_t)b * CN, nullptr, nullptr, nullptr, 0, N_, HID_ / 64, zbuf,
          nullptr, nullptr, 0);
    }
  }
}